// Round 7
// baseline (6708.605 us; speedup 1.0000x reference)
//
#include <hip/hip_runtime.h>

#define TSTEPS 512
#define BATCH  64
#define DIN    256
#define DLAT   512

typedef _Float16 half2_t __attribute__((ext_vector_type(2)));
typedef _Float16 half4_t __attribute__((ext_vector_type(4)));
typedef _Float16 half8_t __attribute__((ext_vector_type(8)));

#if __has_builtin(__builtin_amdgcn_fdot2)
#define FDOT2(a, b, c) __builtin_amdgcn_fdot2((a), (b), (c), false)
#else
#define FDOT2(a, b, c) fmaf((float)(a)[0], (float)(b)[0], fmaf((float)(a)[1], (float)(b)[1], (c)))
#endif

// d_ws layout (bytes):
//   [0, 512K)            : Wp2 fp16 packed W_h
//   [512K, 512K+128K)    : hx exchange buffer, uint[2][64][256] (half2-packed h)
//   [640K, 640K+1K)      : flags int[64][4]
#define WS_HX_OFF   (512u * 1024u)
#define WS_FLAG_OFF (WS_HX_OFF + 2u * 64u * 256u * 4u)
#define WS_NEED     (WS_FLAG_OFF + 64u * 4u * 4u)

// ---------------- Kernel A: P[m,n] = x[m,:] . W_in[n,:] + b_h[n] ----------------
#define BM 64
#define BN 64
#define BK 32

__global__ __launch_bounds__(256)
void precompute_gemm(const float* __restrict__ x,
                     const float* __restrict__ Win,
                     const float* __restrict__ bh,
                     float* __restrict__ P)
{
    __shared__ float As[BM][BK + 1];
    __shared__ float Ws[BN][BK + 1];
    const int m0  = blockIdx.y * BM;
    const int n0  = blockIdx.x * BN;
    const int tid = threadIdx.x;
    const int tx  = tid & 15;
    const int ty  = tid >> 4;
    const int lr  = tid >> 2;
    const int lc  = (tid & 3) * 8;

    float acc[4][4] = {};

    for (int kk = 0; kk < DIN; kk += BK) {
        const float* ax = x   + (size_t)(m0 + lr) * DIN + kk + lc;
        const float* aw = Win + (size_t)(n0 + lr) * DIN + kk + lc;
        float4 a0 = *(const float4*)(ax);
        float4 a1 = *(const float4*)(ax + 4);
        float4 w0 = *(const float4*)(aw);
        float4 w1 = *(const float4*)(aw + 4);
        As[lr][lc+0]=a0.x; As[lr][lc+1]=a0.y; As[lr][lc+2]=a0.z; As[lr][lc+3]=a0.w;
        As[lr][lc+4]=a1.x; As[lr][lc+5]=a1.y; As[lr][lc+6]=a1.z; As[lr][lc+7]=a1.w;
        Ws[lr][lc+0]=w0.x; Ws[lr][lc+1]=w0.y; Ws[lr][lc+2]=w0.z; Ws[lr][lc+3]=w0.w;
        Ws[lr][lc+4]=w1.x; Ws[lr][lc+5]=w1.y; Ws[lr][lc+6]=w1.z; Ws[lr][lc+7]=w1.w;
        __syncthreads();
        #pragma unroll
        for (int k = 0; k < BK; ++k) {
            float a[4], w[4];
            #pragma unroll
            for (int i = 0; i < 4; ++i) a[i] = As[ty*4+i][k];
            #pragma unroll
            for (int j = 0; j < 4; ++j) w[j] = Ws[tx*4+j][k];
            #pragma unroll
            for (int i = 0; i < 4; ++i)
                #pragma unroll
                for (int j = 0; j < 4; ++j)
                    acc[i][j] += a[i] * w[j];
        }
        __syncthreads();
    }

    float4 bv = *(const float4*)(bh + n0 + tx*4);
    #pragma unroll
    for (int i = 0; i < 4; ++i) {
        float4 v;
        v.x = acc[i][0] + bv.x; v.y = acc[i][1] + bv.y;
        v.z = acc[i][2] + bv.z; v.w = acc[i][3] + bv.w;
        *(float4*)(P + (size_t)(m0 + ty*4 + i) * DLAT + n0 + tx*4) = v;
    }
}

// -------- Pack W_h (512x512 fp32 row-major [r][k]) into fp16 k-pair layout -------
// Wp2[kp][r] = half2( W_h[r][2kp], W_h[r][2kp+1] ), kp in [0,256), r in [0,512).
__global__ __launch_bounds__(256)
void pack_wh_fp16(const float* __restrict__ Wh, half2_t* __restrict__ Wp2)
{
    __shared__ float tile[32][33];
    const int x0 = blockIdx.x * 32;    // k tile
    const int y0 = blockIdx.y * 32;    // r tile
    const int tx = threadIdx.x, ty = threadIdx.y;   // (32, 8)
    #pragma unroll
    for (int j = 0; j < 32; j += 8)
        tile[ty + j][tx] = Wh[(size_t)(y0 + ty + j) * DLAT + x0 + tx]; // tile[r][k]
    __syncthreads();
    #pragma unroll
    for (int j = 0; j < 16; j += 8) {
        const int kp = ty + j;                       // 0..15
        half2_t v;
        v[0] = (_Float16)tile[tx][2 * kp];
        v[1] = (_Float16)tile[tx][2 * kp + 1];
        Wp2[(size_t)((x0 >> 1) + kp) * DLAT + y0 + tx] = v;
    }
}

// ---------------- Kernel B: 4-way split scan with L3 handshake -------------------
// 256 WGs: WG(b,q) owns output rows [128q, 128q+128) of chain b. 512 threads =
// 8 waves; wave w owns k-pairs [32w, 32w+32); lane g owns rows 128q+{2g,2g+1}.
// W per thread = 32 kp x 2 rows = 64 VGPRs, fully arch-resident (no AGPR tax,
// no LDS W). Per step: dot2 partials -> barrier -> 128-thread reduce+relu ->
// publish packed h-slice via agent-scope atomic stores + release flag; partners
// spin (lane0-only) on acquire flags, assemble h via agent-scope atomic loads
// (coherent point; per-XCD L2s are not coherent). hx double-buffered by step
// parity (skew bounded at 1 step by the flag wait). Flags memset to 0 each
// launch (persist across graph replays otherwise).
__global__ __launch_bounds__(512)
void rnn_scan_quad(const half2_t* __restrict__ Wp2,   // [256 kp][512 r]
                   const float* __restrict__ h0,
                   float* __restrict__ out,           // P in, h_seq out (in place)
                   unsigned int* __restrict__ hx,     // [2][64][256] packed half2
                   int* __restrict__ flags)           // [64][4]
{
    __shared__ half2_t hh[DLAT / 2];   // full h as half2 (1 KB)
    __shared__ float   p[8][128];      // partials (4 KB)

    const int b   = blockIdx.x >> 2;
    const int q   = blockIdx.x & 3;
    const int tid = threadIdx.x;
    const int w   = tid >> 6;          // wave id = k-group
    const int g   = tid & 63;          // lane: rows 128q+2g, +1

    // ---- one-time: W into 64 arch VGPRs (32 kp x 2 adjacent rows = half4) ----
    half4_t wr[32];
    {
        const half4_t* src = (const half4_t*)Wp2;   // half4 idx = (kp*512 + r)/2
        #pragma unroll
        for (int i = 0; i < 32; ++i)
            wr[i] = src[((size_t)(w * 32 + i) * DLAT + q * 128 + 2 * g) >> 1];
    }

    // ---- h(0) = h0 (pre-relu), assembled locally by every WG ----
    ((_Float16*)hh)[tid] = (_Float16)h0[(size_t)b * DLAT + tid];
    __syncthreads();

    int* myflag = &flags[b * 4 + q];
    const int qo[3] = { (q + 1) & 3, (q + 2) & 3, (q + 3) & 3 };

    for (int t = 0; t < TSTEPS; ++t) {
        // ---- assemble partner slices of h(t) (t=0: all local already) ----
        if (t > 0) {
            if (tid < 192) {
                const int pi = tid >> 6;          // 0..2 (one wave per partner)
                const int qq = qo[pi];
                if (g == 0) {                     // lane 0 spins; wave reconverges
                    while (__hip_atomic_load(&flags[b * 4 + qq], __ATOMIC_ACQUIRE,
                                             __HIP_MEMORY_SCOPE_AGENT) < t)
                        __builtin_amdgcn_s_sleep(1);
                }
                unsigned int u = __hip_atomic_load(
                    &hx[(size_t)((t & 1) * BATCH + b) * 256 + qq * 64 + g],
                    __ATOMIC_RELAXED, __HIP_MEMORY_SCOPE_AGENT);
                ((unsigned int*)hh)[qq * 64 + g] = u;
            }
            __syncthreads();
        }

        // ---- prefetch P for this WG's rows (covers dot2 phase) ----
        float pv = 0.f;
        float* orow = out + ((size_t)t * BATCH + b) * DLAT + q * 128;
        if (tid < 128) pv = orow[tid];

        // ---- dot2 partials over this wave's 32 k-pairs ----
        float accA = 0.f, accB = 0.f;
        const half8_t* hh8 = (const half8_t*)hh;
        #pragma unroll
        for (int c = 0; c < 8; ++c) {
            half8_t hc = hh8[w * 8 + c];          // wave-uniform broadcast, 4 kp
            #pragma unroll
            for (int j = 0; j < 4; ++j) {
                const int i = c * 4 + j;
                half2_t hv; hv[0] = hc[2 * j]; hv[1] = hc[2 * j + 1];
                half2_t wA; wA[0] = wr[i][0]; wA[1] = wr[i][1];
                half2_t wB; wB[0] = wr[i][2]; wB[1] = wr[i][3];
                accA = FDOT2(wA, hv, accA);
                accB = FDOT2(wB, hv, accB);
            }
        }
        *(float2*)&p[w][2 * g] = make_float2(accA, accB);
        __syncthreads();                          // partials ready

        // ---- reduce + relu + publish (threads 0..127, rows 128q+tid) ----
        float v = 0.f;
        if (tid < 128) {
            v = pv;
            #pragma unroll
            for (int ww = 0; ww < 8; ++ww) v += p[ww][tid];
            v = fmaxf(v, 0.f);
            orow[tid] = v;
            ((_Float16*)hh)[q * 128 + tid] = (_Float16)v;   // own slice for next step
        }
        // pack pairs in-register via shfl and publish to coherent point
        float vo = __shfl_down(v, 1);
        if (tid < 128 && (tid & 1) == 0) {
            half2_t h2; h2[0] = (_Float16)v; h2[1] = (_Float16)vo;
            unsigned int u;
            __builtin_memcpy(&u, &h2, 4);
            __hip_atomic_store(
                &hx[(size_t)(((t + 1) & 1) * BATCH + b) * 256 + q * 64 + (tid >> 1)],
                u, __ATOMIC_RELAXED, __HIP_MEMORY_SCOPE_AGENT);
        }
        __syncthreads();   // drains vmcnt: all hx stores complete before flag
        if (tid == 0)
            __hip_atomic_store(myflag, t + 1, __ATOMIC_RELEASE,
                               __HIP_MEMORY_SCOPE_AGENT);
        // hh own-slice writes are covered by this barrier too
    }
}

// ---------------- Fallback (no workspace): row-major W_h, one row per thread ----
__global__ __launch_bounds__(512)
void rnn_scan_row(const float* __restrict__ Wh,
                  const float* __restrict__ h0,
                  float* __restrict__ out)
{
    __shared__ float h[DLAT];
    const int b = blockIdx.x;
    const int r = threadIdx.x;
    h[r] = h0[(size_t)b * DLAT + r];
    __syncthreads();
    const float* wrow = Wh + (size_t)r * DLAT;
    for (int t = 0; t < TSTEPS; ++t) {
        float* orow = out + ((size_t)t * BATCH + b) * DLAT;
        float acc = orow[r];
        #pragma unroll 8
        for (int k = 0; k < DLAT; k += 4) {
            float4 w  = *(const float4*)(wrow + k);
            float4 hv = *(const float4*)&h[k];
            acc += w.x*hv.x + w.y*hv.y + w.z*hv.z + w.w*hv.w;
        }
        float v = fmaxf(acc, 0.f);
        __syncthreads();
        h[r] = v;
        orow[r] = v;
        __syncthreads();
    }
}

extern "C" void kernel_launch(void* const* d_in, const int* in_sizes, int n_in,
                              void* d_out, int out_size, void* d_ws, size_t ws_size,
                              hipStream_t stream)
{
    const float* x    = (const float*)d_in[0];
    const float* h0   = (const float*)d_in[1];
    const float* Win  = (const float*)d_in[2];
    const float* Wh   = (const float*)d_in[3];
    const float* bh   = (const float*)d_in[4];
    float* out = (float*)d_out;

    dim3 gA(DLAT / BN, (TSTEPS * BATCH) / BM);   // (8, 512)
    precompute_gemm<<<gA, 256, 0, stream>>>(x, Win, bh, out);

    if (ws_size >= WS_NEED) {
        half2_t*      Wp2   = (half2_t*)d_ws;
        unsigned int* hx    = (unsigned int*)((char*)d_ws + WS_HX_OFF);
        int*          flags = (int*)((char*)d_ws + WS_FLAG_OFF);
        pack_wh_fp16<<<dim3(16, 16), dim3(32, 8), 0, stream>>>(Wh, Wp2);
        hipMemsetAsync(flags, 0, BATCH * 4 * sizeof(int), stream);
        rnn_scan_quad<<<BATCH * 4, 512, 0, stream>>>(Wp2, h0, out, hx, flags);
    } else {
        rnn_scan_row<<<BATCH, 512, 0, stream>>>(Wh, h0, out);
    }
}

// Round 8
// 1378.411 us; speedup vs baseline: 4.8669x; 4.8669x over previous
//
#include <hip/hip_runtime.h>

#define TSTEPS 512
#define BATCH  64
#define DIN    256
#define DLAT   512

typedef _Float16 half8_t __attribute__((ext_vector_type(8)));
typedef float    f32x4  __attribute__((ext_vector_type(4)));

// d_ws layout: [0, 512K) = Wm, MFMA-fragment-packed fp16 W_h
#define WS_NEED (512u * 1024u)

// ---------------- Kernel A: P[m,n] = x[m,:] . W_in[n,:] + b_h[n] ----------------
#define BM 64
#define BN 64
#define BK 32

__global__ __launch_bounds__(256)
void precompute_gemm(const float* __restrict__ x,
                     const float* __restrict__ Win,
                     const float* __restrict__ bh,
                     float* __restrict__ P)
{
    __shared__ float As[BM][BK + 1];
    __shared__ float Ws[BN][BK + 1];
    const int m0  = blockIdx.y * BM;
    const int n0  = blockIdx.x * BN;
    const int tid = threadIdx.x;
    const int tx  = tid & 15;
    const int ty  = tid >> 4;
    const int lr  = tid >> 2;
    const int lc  = (tid & 3) * 8;

    float acc[4][4] = {};

    for (int kk = 0; kk < DIN; kk += BK) {
        const float* ax = x   + (size_t)(m0 + lr) * DIN + kk + lc;
        const float* aw = Win + (size_t)(n0 + lr) * DIN + kk + lc;
        float4 a0 = *(const float4*)(ax);
        float4 a1 = *(const float4*)(ax + 4);
        float4 w0 = *(const float4*)(aw);
        float4 w1 = *(const float4*)(aw + 4);
        As[lr][lc+0]=a0.x; As[lr][lc+1]=a0.y; As[lr][lc+2]=a0.z; As[lr][lc+3]=a0.w;
        As[lr][lc+4]=a1.x; As[lr][lc+5]=a1.y; As[lr][lc+6]=a1.z; As[lr][lc+7]=a1.w;
        Ws[lr][lc+0]=w0.x; Ws[lr][lc+1]=w0.y; Ws[lr][lc+2]=w0.z; Ws[lr][lc+3]=w0.w;
        Ws[lr][lc+4]=w1.x; Ws[lr][lc+5]=w1.y; Ws[lr][lc+6]=w1.z; Ws[lr][lc+7]=w1.w;
        __syncthreads();
        #pragma unroll
        for (int k = 0; k < BK; ++k) {
            float a[4], w[4];
            #pragma unroll
            for (int i = 0; i < 4; ++i) a[i] = As[ty*4+i][k];
            #pragma unroll
            for (int j = 0; j < 4; ++j) w[j] = Ws[tx*4+j][k];
            #pragma unroll
            for (int i = 0; i < 4; ++i)
                #pragma unroll
                for (int j = 0; j < 4; ++j)
                    acc[i][j] += a[i] * w[j];
        }
        __syncthreads();
    }

    float4 bv = *(const float4*)(bh + n0 + tx*4);
    #pragma unroll
    for (int i = 0; i < 4; ++i) {
        float4 v;
        v.x = acc[i][0] + bv.x; v.y = acc[i][1] + bv.y;
        v.z = acc[i][2] + bv.z; v.w = acc[i][3] + bv.w;
        *(float4*)(P + (size_t)(m0 + ty*4 + i) * DLAT + n0 + tx*4) = v;
    }
}

// -------- Pack W_h into MFMA B-fragment order (fp16) -----------------------------
// Tile (kt, ntg): 32 k x 16 n. Fragment element (lane, e) holds
// W_h[n = ntg*16 + (lane&15)][k = kt*32 + (lane>>4)*8 + e]. Stored flat:
// Wm[(tile*64 + lane)*8 + e], tile = kt*32 + ntg. The scan kernel loads A (h)
// with the SAME (lane>>4)*8+e k-formula, so any HW-internal k permutation
// cancels (dot over k is permutation-invariant).
__global__ __launch_bounds__(256)
void pack_wh_mfma(const float* __restrict__ Wh, _Float16* __restrict__ Wm)
{
    const int idx  = blockIdx.x * 256 + threadIdx.x;  // 32768 = 512 tiles x 64 lanes
    const int lane = idx & 63;
    const int tile = idx >> 6;
    const int kt   = tile >> 5;
    const int ntg  = tile & 31;
    const int n    = ntg * 16 + (lane & 15);
    const int k0   = kt * 32 + (lane >> 4) * 8;
    half8_t v;
    #pragma unroll
    for (int e = 0; e < 8; ++e)
        v[e] = (_Float16)Wh[(size_t)n * DLAT + k0 + e];
    *(half8_t*)(Wm + (size_t)idx * 8) = v;
}

// ---------------- Kernel B: MFMA scan, W resident in AGPR/VGPR + LDS ------------
// One chain per WG; 256 threads = 4 waves, 1 wave/SIMD (512-reg unified budget).
// Wave w owns n-range [128w, 128w+128) = 8 n-tiles; all 16 k-tiles -> 128 MFMA
// per step per wave, no cross-wave reduction. B-frags: kt 0..11 persistent in
// registers (96 frags = 384 regs; MFMA reads AGPRs natively -> zero per-use
// copy cost, unlike R4-R6's v_accvgpr_read tax on dot2), kt 12..15 in LDS
// (128 KB, [frag][lane] b128 conflict-free). A = h broadcast: every lane loads
// the same 16B h-chunk -> all 16 A-rows identical -> C[*][n] all equal the
// answer; lanes 0..15 read C[nt][0] (col = lane&15, HW-verified mapping).
// hh double-buffered -> ONE barrier per step.
__global__ __launch_bounds__(256, 1)
void rnn_scan_mfma(const half8_t* __restrict__ Wm,   // fragment-packed
                   const float* __restrict__ h0,
                   float* __restrict__ out)          // P in, h_seq out (in place)
{
    __shared__ half8_t  ldsB[4 * 32 * 64];   // 128 KB: [(w*32 + slot)*64 + lane]
    __shared__ _Float16 hbuf[2][DLAT];       // 2 KB, double-buffered h

    const int b    = blockIdx.x;
    const int tid  = threadIdx.x;
    const int w    = tid >> 6;               // wave 0..3: n-range 128w
    const int lane = tid & 63;

    // ---- one-time: B fragments into registers (kt 0..11) and LDS (12..15) ----
    half8_t bfr[96];
    #pragma unroll
    for (int kt = 0; kt < 12; ++kt)
        #pragma unroll
        for (int nt = 0; nt < 8; ++nt)
            bfr[kt * 8 + nt] = Wm[(size_t)((kt * 32 + w * 8 + nt) * 64) + lane];
    #pragma unroll
    for (int kt = 12; kt < 16; ++kt)
        #pragma unroll
        for (int nt = 0; nt < 8; ++nt)
            ldsB[(w * 32 + (kt - 12) * 8 + nt) * 64 + lane] =
                Wm[(size_t)((kt * 32 + w * 8 + nt) * 64) + lane];

    // ---- h(0) = h0 (pre-relu; negatives contribute) ----
    hbuf[0][tid]       = (_Float16)h0[(size_t)b * DLAT + tid];
    hbuf[0][tid + 256] = (_Float16)h0[(size_t)b * DLAT + tid + 256];
    __syncthreads();

    for (int t = 0; t < TSTEPS; ++t) {
        const int cur = t & 1, nxt = cur ^ 1;
        float* orow = out + ((size_t)t * BATCH + b) * DLAT;

        // prefetch P for this wave's 8 n-tiles (lanes 0..15 active)
        float pv[8];
        if (lane < 16) {
            #pragma unroll
            for (int nt = 0; nt < 8; ++nt)
                pv[nt] = orow[w * 128 + nt * 16 + lane];
        }

        f32x4 C[8] = {};
        #pragma unroll
        for (int kt = 0; kt < 16; ++kt) {
            // broadcast A: all lanes in a 16-lane group read the same 16B h chunk
            half8_t A = *(const half8_t*)&hbuf[cur][kt * 32 + (lane >> 4) * 8];
            #pragma unroll
            for (int nt = 0; nt < 8; ++nt) {
                half8_t B = (kt < 12)
                    ? bfr[kt * 8 + nt]
                    : ldsB[(w * 32 + (kt - 12) * 8 + nt) * 64 + lane];
                C[nt] = __builtin_amdgcn_mfma_f32_16x16x32_f16(A, B, C[nt], 0, 0, 0);
            }
        }

        // epilogue: lanes 0..15 own n = 128w + nt*16 + lane
        if (lane < 16) {
            #pragma unroll
            for (int nt = 0; nt < 8; ++nt) {
                float v = fmaxf(C[nt][0] + pv[nt], 0.f);
                orow[w * 128 + nt * 16 + lane] = v;
                hbuf[nxt][w * 128 + nt * 16 + lane] = (_Float16)v;
            }
        }
        __syncthreads();   // hh(next) visible to all waves
    }
}

// ---------------- Fallback (no workspace): row-major W_h, one row per thread ----
__global__ __launch_bounds__(512)
void rnn_scan_row(const float* __restrict__ Wh,
                  const float* __restrict__ h0,
                  float* __restrict__ out)
{
    __shared__ float h[DLAT];
    const int b = blockIdx.x;
    const int r = threadIdx.x;
    h[r] = h0[(size_t)b * DLAT + r];
    __syncthreads();
    const float* wrow = Wh + (size_t)r * DLAT;
    for (int t = 0; t < TSTEPS; ++t) {
        float* orow = out + ((size_t)t * BATCH + b) * DLAT;
        float acc = orow[r];
        #pragma unroll 8
        for (int k = 0; k < DLAT; k += 4) {
            float4 w  = *(const float4*)(wrow + k);
            float4 hv = *(const float4*)&h[k];
            acc += w.x*hv.x + w.y*hv.y + w.z*hv.z + w.w*hv.w;
        }
        float v = fmaxf(acc, 0.f);
        __syncthreads();
        h[r] = v;
        orow[r] = v;
        __syncthreads();
    }
}

extern "C" void kernel_launch(void* const* d_in, const int* in_sizes, int n_in,
                              void* d_out, int out_size, void* d_ws, size_t ws_size,
                              hipStream_t stream)
{
    const float* x    = (const float*)d_in[0];
    const float* h0   = (const float*)d_in[1];
    const float* Win  = (const float*)d_in[2];
    const float* Wh   = (const float*)d_in[3];
    const float* bh   = (const float*)d_in[4];
    float* out = (float*)d_out;

    dim3 gA(DLAT / BN, (TSTEPS * BATCH) / BM);   // (8, 512)
    precompute_gemm<<<gA, 256, 0, stream>>>(x, Win, bh, out);

    if (ws_size >= WS_NEED) {
        _Float16* Wm = (_Float16*)d_ws;
        pack_wh_mfma<<<128, 256, 0, stream>>>(Wh, Wm);
        rnn_scan_mfma<<<BATCH, 256, 0, stream>>>((const half8_t*)Wm, h0, out);
    } else {
        rnn_scan_row<<<BATCH, 512, 0, stream>>>(Wh, h0, out);
    }
}

// Round 9
// 870.739 us; speedup vs baseline: 7.7045x; 1.5830x over previous
//
#include <hip/hip_runtime.h>

#define TSTEPS 512
#define BATCH  64
#define DIN    256
#define DLAT   512

typedef _Float16 half8_t __attribute__((ext_vector_type(8)));
typedef float    f32x4  __attribute__((ext_vector_type(4)));

// d_ws layout: [0, 512K) = Wm, MFMA-fragment-packed fp16 W_h
#define WS_NEED (512u * 1024u)

// ---------------- Kernel A: P[m,n] = x[m,:] . W_in[n,:] + b_h[n] ----------------
#define BM 64
#define BN 64
#define BK 32

__global__ __launch_bounds__(256)
void precompute_gemm(const float* __restrict__ x,
                     const float* __restrict__ Win,
                     const float* __restrict__ bh,
                     float* __restrict__ P)
{
    __shared__ float As[BM][BK + 1];
    __shared__ float Ws[BN][BK + 1];
    const int m0  = blockIdx.y * BM;
    const int n0  = blockIdx.x * BN;
    const int tid = threadIdx.x;
    const int tx  = tid & 15;
    const int ty  = tid >> 4;
    const int lr  = tid >> 2;
    const int lc  = (tid & 3) * 8;

    float acc[4][4] = {};

    for (int kk = 0; kk < DIN; kk += BK) {
        const float* ax = x   + (size_t)(m0 + lr) * DIN + kk + lc;
        const float* aw = Win + (size_t)(n0 + lr) * DIN + kk + lc;
        float4 a0 = *(const float4*)(ax);
        float4 a1 = *(const float4*)(ax + 4);
        float4 w0 = *(const float4*)(aw);
        float4 w1 = *(const float4*)(aw + 4);
        As[lr][lc+0]=a0.x; As[lr][lc+1]=a0.y; As[lr][lc+2]=a0.z; As[lr][lc+3]=a0.w;
        As[lr][lc+4]=a1.x; As[lr][lc+5]=a1.y; As[lr][lc+6]=a1.z; As[lr][lc+7]=a1.w;
        Ws[lr][lc+0]=w0.x; Ws[lr][lc+1]=w0.y; Ws[lr][lc+2]=w0.z; Ws[lr][lc+3]=w0.w;
        Ws[lr][lc+4]=w1.x; Ws[lr][lc+5]=w1.y; Ws[lr][lc+6]=w1.z; Ws[lr][lc+7]=w1.w;
        __syncthreads();
        #pragma unroll
        for (int k = 0; k < BK; ++k) {
            float a[4], w[4];
            #pragma unroll
            for (int i = 0; i < 4; ++i) a[i] = As[ty*4+i][k];
            #pragma unroll
            for (int j = 0; j < 4; ++j) w[j] = Ws[tx*4+j][k];
            #pragma unroll
            for (int i = 0; i < 4; ++i)
                #pragma unroll
                for (int j = 0; j < 4; ++j)
                    acc[i][j] += a[i] * w[j];
        }
        __syncthreads();
    }

    float4 bv = *(const float4*)(bh + n0 + tx*4);
    #pragma unroll
    for (int i = 0; i < 4; ++i) {
        float4 v;
        v.x = acc[i][0] + bv.x; v.y = acc[i][1] + bv.y;
        v.z = acc[i][2] + bv.z; v.w = acc[i][3] + bv.w;
        *(float4*)(P + (size_t)(m0 + ty*4 + i) * DLAT + n0 + tx*4) = v;
    }
}

// -------- Pack W_h into MFMA B-fragment order (fp16) -----------------------------
// Tile (kt, ntg): 32 k x 16 n. Fragment element (lane, e) holds
// W_h[n = ntg*16 + (lane&15)][k = kt*32 + (lane>>4)*8 + e]. Stored flat:
// Wm[(tile*64 + lane)*8 + e], tile = kt*32 + ntg. The scan kernel loads A (h)
// with the SAME (lane>>4)*8+e k-formula, so any HW-internal k permutation
// cancels (dot over k is permutation-invariant). Verified on HW in R8
// (absmax 0.03125).
__global__ __launch_bounds__(256)
void pack_wh_mfma(const float* __restrict__ Wh, _Float16* __restrict__ Wm)
{
    const int idx  = blockIdx.x * 256 + threadIdx.x;  // 32768 = 512 tiles x 64 lanes
    const int lane = idx & 63;
    const int tile = idx >> 6;
    const int kt   = tile >> 5;
    const int ntg  = tile & 31;
    const int n    = ntg * 16 + (lane & 15);
    const int k0   = kt * 32 + (lane >> 4) * 8;
    half8_t v;
    #pragma unroll
    for (int e = 0; e < 8; ++e)
        v[e] = (_Float16)Wh[(size_t)n * DLAT + k0 + e];
    *(half8_t*)(Wm + (size_t)idx * 8) = v;
}

// ---------------- Kernel B: MFMA scan, 8 waves (2/SIMD) for latency hiding ------
// One chain per WG; 512 threads = 8 waves, 2 waves/SIMD (256-reg budget each).
// Wave w owns n-range [64w, 64w+64) = 4 n-tiles x 16 k-tiles = 64 MFMA/step;
// no cross-wave reduction. B-frags per wave: f = kt*4+nt; f<46 in registers
// (184 regs; overflow lands in AGPRs which MFMA reads natively - zero tax),
// f>=46 in LDS (18 frags x 8 waves = 144 KB, [frag][lane] b128 conflict-free).
// A = h broadcast (all 16 rows identical -> C rows identical). Epilogue uses
// ALL 64 lanes: lane L owns output n = 64w + L; value = C[L>>4][0] selected
// by cndmask chain (compile-time C indices). hbuf double-buffered -> one
// barrier per step; SIMD-partner wave hides ds_read/MFMA dependency stalls.
__global__ __launch_bounds__(512, 2)
void rnn_scan_mfma8(const half8_t* __restrict__ Wm,   // fragment-packed
                    const float* __restrict__ h0,
                    float* __restrict__ out)          // P in, h_seq out (in place)
{
    __shared__ half8_t  ldsB[8 * 18 * 64];   // 144 KB: [(w*18 + fl)*64 + lane]
    __shared__ _Float16 hbuf[2][DLAT];       // 2 KB, double-buffered h

    const int b    = blockIdx.x;
    const int tid  = threadIdx.x;
    const int w    = tid >> 6;               // wave 0..7: n-range 64w
    const int lane = tid & 63;

    // ---- one-time: B fragments into registers (f<46) and LDS (f>=46) ----
    // Wm tile index = kt*32 + ntg, ntg = w*4 + nt; f = kt*4 + nt.
    half8_t bfr[46];
    #pragma unroll
    for (int kt = 0; kt < 16; ++kt)
        #pragma unroll
        for (int nt = 0; nt < 4; ++nt) {
            const int f = kt * 4 + nt;
            half8_t v = Wm[(size_t)((kt * 32 + w * 4 + nt) * 64) + lane];
            if (f < 46) bfr[f] = v;
            else        ldsB[(w * 18 + (f - 46)) * 64 + lane] = v;
        }

    // ---- h(0) = h0 (pre-relu; negatives contribute) ----
    hbuf[0][tid] = (_Float16)h0[(size_t)b * DLAT + tid];
    __syncthreads();

    for (int t = 0; t < TSTEPS; ++t) {
        const int cur = t & 1, nxt = cur ^ 1;
        float* orow = out + ((size_t)t * BATCH + b) * DLAT;

        // prefetch P: lane L owns n = 64w + L (coalesced; hidden under MFMAs)
        float pv = orow[w * 64 + lane];

        f32x4 C[4] = {};
        #pragma unroll
        for (int kt = 0; kt < 16; ++kt) {
            // broadcast A: 16-lane groups read the same 16B h chunk
            half8_t A = *(const half8_t*)&hbuf[cur][kt * 32 + (lane >> 4) * 8];
            #pragma unroll
            for (int nt = 0; nt < 4; ++nt) {
                const int f = kt * 4 + nt;
                half8_t B = (f < 46) ? bfr[f]
                                     : ldsB[(w * 18 + (f - 46)) * 64 + lane];
                C[nt] = __builtin_amdgcn_mfma_f32_16x16x32_f16(A, B, C[nt], 0, 0, 0);
            }
        }

        // epilogue: all 64 lanes; lane L -> nt = L>>4, col = L&15, n = 64w + L
        const int g4 = lane >> 4;
        float m = (g4 == 0) ? C[0][0]
                : (g4 == 1) ? C[1][0]
                : (g4 == 2) ? C[2][0]
                :             C[3][0];     // all C rows equal (broadcast A)
        float v = fmaxf(m + pv, 0.f);
        orow[w * 64 + lane] = v;
        hbuf[nxt][w * 64 + lane] = (_Float16)v;
        __syncthreads();   // h(t+1) visible to all waves
    }
}

// ---------------- Fallback (no workspace): row-major W_h, one row per thread ----
__global__ __launch_bounds__(512)
void rnn_scan_row(const float* __restrict__ Wh,
                  const float* __restrict__ h0,
                  float* __restrict__ out)
{
    __shared__ float h[DLAT];
    const int b = blockIdx.x;
    const int r = threadIdx.x;
    h[r] = h0[(size_t)b * DLAT + r];
    __syncthreads();
    const float* wrow = Wh + (size_t)r * DLAT;
    for (int t = 0; t < TSTEPS; ++t) {
        float* orow = out + ((size_t)t * BATCH + b) * DLAT;
        float acc = orow[r];
        #pragma unroll 8
        for (int k = 0; k < DLAT; k += 4) {
            float4 w  = *(const float4*)(wrow + k);
            float4 hv = *(const float4*)&h[k];
            acc += w.x*hv.x + w.y*hv.y + w.z*hv.z + w.w*hv.w;
        }
        float v = fmaxf(acc, 0.f);
        __syncthreads();
        h[r] = v;
        orow[r] = v;
        __syncthreads();
    }
}

extern "C" void kernel_launch(void* const* d_in, const int* in_sizes, int n_in,
                              void* d_out, int out_size, void* d_ws, size_t ws_size,
                              hipStream_t stream)
{
    const float* x    = (const float*)d_in[0];
    const float* h0   = (const float*)d_in[1];
    const float* Win  = (const float*)d_in[2];
    const float* Wh   = (const float*)d_in[3];
    const float* bh   = (const float*)d_in[4];
    float* out = (float*)d_out;

    dim3 gA(DLAT / BN, (TSTEPS * BATCH) / BM);   // (8, 512)
    precompute_gemm<<<gA, 256, 0, stream>>>(x, Win, bh, out);

    if (ws_size >= WS_NEED) {
        _Float16* Wm = (_Float16*)d_ws;
        pack_wh_mfma<<<128, 256, 0, stream>>>(Wh, Wm);
        rnn_scan_mfma8<<<BATCH, 512, 0, stream>>>((const half8_t*)Wm, h0, out);
    } else {
        rnn_scan_row<<<BATCH, 512, 0, stream>>>(Wh, h0, out);
    }
}